// Round 3
// baseline (25179.337 us; speedup 1.0000x reference)
//
#include <hip/hip_runtime.h>
#include <hip/hip_bf16.h>

#define S_LEN 2048
#define BATCH 64
#define HID   512
#define GATES 2048   // 4*HID
#define DIN   512
#define NBLK  32     // recurrent persistent blocks

typedef __attribute__((ext_vector_type(8))) short short8v;
typedef __attribute__((ext_vector_type(4))) float f32x4;

__device__ inline unsigned short f2bf(float f) {
  union { float f; unsigned u; } a; a.f = f;
  unsigned r = a.u + 0x7fffu + ((a.u >> 16) & 1u);
  return (unsigned short)(r >> 16);
}
__device__ inline float bf2f(unsigned short h) {
  union { unsigned u; float f; } a; a.u = ((unsigned)h) << 16; return a.f;
}

// ---------- kernel 1: split x (fp32) -> bf16 hi + lo ----------
__global__ __launch_bounds__(256) void k_split_x(const float* __restrict__ x,
                                                 unsigned short* __restrict__ xhi,
                                                 unsigned short* __restrict__ xlo) {
  const long total = (long)S_LEN * BATCH * DIN / 4;
  long i = (long)blockIdx.x * blockDim.x + threadIdx.x;
  const long stride = (long)gridDim.x * blockDim.x;
  for (; i < total; i += stride) {
    float4 v = ((const float4*)x)[i];
    ushort4 hv, lv;
    hv.x = f2bf(v.x); lv.x = f2bf(v.x - bf2f(hv.x));
    hv.y = f2bf(v.y); lv.y = f2bf(v.y - bf2f(hv.y));
    hv.z = f2bf(v.z); lv.z = f2bf(v.z - bf2f(hv.z));
    hv.w = f2bf(v.w); lv.w = f2bf(v.w - bf2f(hv.w));
    ((ushort4*)xhi)[i] = hv;
    ((ushort4*)xlo)[i] = lv;
  }
}

// ---------- kernel 2: weights -> bf16, bias sum ----------
__global__ __launch_bounds__(256) void k_prep_w(const float* __restrict__ Wih,
                                                const float* __restrict__ Whh,
                                                const float* __restrict__ bih,
                                                const float* __restrict__ bhh,
                                                unsigned short* __restrict__ WihB,
                                                unsigned short* __restrict__ WhhB,
                                                float* __restrict__ bias) {
  int i = blockIdx.x * 256 + threadIdx.x;
  if (i < GATES * DIN) {
    WihB[i] = f2bf(Wih[i]);
    WhhB[i] = f2bf(Whh[i]);
  }
  if (i < GATES) bias[i] = bih[i] + bhh[i];
}

// ---------- kernel 3: pre[t][u][b][gate] = x[t,b,:]·Wih[gate*512+u,:] + biases ----------
#define BM 128
#define BN 128
#define BK 32
#define LDSROW 40

__global__ __launch_bounds__(256) void k_gemm_pre(
    const unsigned short* __restrict__ A,   // WihB [2048][512]
    const unsigned short* __restrict__ Bh,  // xhi  [131072][512]
    const unsigned short* __restrict__ Bl,  // xlo
    const float* __restrict__ bias,
    unsigned short* __restrict__ pre)       // [S][512 u][64 b][4 gate] bf16
{
  __shared__ unsigned short As [BM * LDSROW];
  __shared__ unsigned short Bhs[BM * LDSROW];
  __shared__ unsigned short Bls[BM * LDSROW];

  const int tid  = threadIdx.x;
  const int lane = tid & 63;
  const int wave = tid >> 6;
  const int bm = blockIdx.x & 15;
  const int bn = blockIdx.x >> 4;
  const int wr = wave >> 1, wc = wave & 1;

  f32x4 acc[4][4];
  #pragma unroll
  for (int i = 0; i < 4; ++i)
    #pragma unroll
    for (int j = 0; j < 4; ++j) acc[i][j] = (f32x4){0.f, 0.f, 0.f, 0.f};

  const long arow0 = (long)bm * BM;
  const long brow0 = (long)bn * BN;

  for (int kt = 0; kt < DIN / BK; ++kt) {
    #pragma unroll
    for (int it = 0; it < 2; ++it) {
      int c = tid + it * 256;
      int row = c >> 2, kc = c & 3;
      int lbyte = row * (LDSROW * 2) + kc * 16;
      long ga = (arow0 + row) * 512 + kt * BK + kc * 8;
      long gb = (brow0 + row) * 512 + kt * BK + kc * 8;
      *(short8v*)((char*)As  + lbyte) = *(const short8v*)(A  + ga);
      *(short8v*)((char*)Bhs + lbyte) = *(const short8v*)(Bh + gb);
      *(short8v*)((char*)Bls + lbyte) = *(const short8v*)(Bl + gb);
    }
    __syncthreads();

    short8v a[4], bh[4], bl[4];
    #pragma unroll
    for (int mt = 0; mt < 4; ++mt) {
      int r = wr * 64 + mt * 16 + (lane & 15);
      a[mt] = *(const short8v*)((const char*)As + r * (LDSROW * 2) + (lane >> 4) * 16);
    }
    #pragma unroll
    for (int nt = 0; nt < 4; ++nt) {
      int r = wc * 64 + nt * 16 + (lane & 15);
      bh[nt] = *(const short8v*)((const char*)Bhs + r * (LDSROW * 2) + (lane >> 4) * 16);
      bl[nt] = *(const short8v*)((const char*)Bls + r * (LDSROW * 2) + (lane >> 4) * 16);
    }
    #pragma unroll
    for (int mt = 0; mt < 4; ++mt)
      #pragma unroll
      for (int nt = 0; nt < 4; ++nt) {
        acc[mt][nt] = __builtin_amdgcn_mfma_f32_16x16x32_bf16(a[mt], bh[nt], acc[mt][nt], 0, 0, 0);
        acc[mt][nt] = __builtin_amdgcn_mfma_f32_16x16x32_bf16(a[mt], bl[nt], acc[mt][nt], 0, 0, 0);
      }
    __syncthreads();
  }

  #pragma unroll
  for (int mt = 0; mt < 4; ++mt) {
    #pragma unroll
    for (int j = 0; j < 4; ++j) {
      int m = bm * BM + wr * 64 + mt * 16 + (lane >> 4) * 4 + j;  // gate-row 0..2047
      int gate = m >> 9;
      int u    = m & 511;
      float bv = bias[m];
      #pragma unroll
      for (int nt = 0; nt < 4; ++nt) {
        int n = bn * BN + wc * 64 + nt * 16 + (lane & 15);
        int t = n >> 6, b = n & 63;
        pre[(((long)t * 512 + u) * 64 + b) * 4 + gate] = f2bf(acc[mt][nt][j] + bv);
      }
    }
  }
}

// ---------- kernel 4: persistent recurrence, wave-autonomous ----------
// 32 blocks x 512 threads = 256 waves. Wave (q = wave&3, uo = g*2 + (wave>>2))
// owns batches [q*16, q*16+16) x units [uo*8, uo*8+8). Batch-quad q's waves form
// an independent 64-wave recurrence (4 disjoint groups, no cross-group sync).
// No LDS, no __syncthreads. W_hh fragments pinned in VGPRs via asm "+v".
// Per-wave flags; relaxed agent-scope (sc1) atomics; writer drains own vmcnt
// before publishing (MALL is the common coherence point; proven in round 2).
__global__ __launch_bounds__(512, 2) void k_lstm(
    const unsigned short* __restrict__ pre,   // [S][512][64][4] bf16
    const unsigned short* __restrict__ WhhB,  // [2048][512] bf16
    unsigned short* __restrict__ hbuf,        // [2][64 b][512 u] bf16
    int* __restrict__ flags,                  // [4][64]
    float* __restrict__ out)                  // [S*B*H | h_f | c_f]
{
  const int tid  = threadIdx.x;
  const int lane = tid & 63;
  const int wave = tid >> 6;
  const int g    = blockIdx.x;
  const int q    = wave & 3;           // batch quad
  const int uo   = g * 2 + (wave >> 2);  // unit octet 0..63
  const int ub   = uo * 8;             // first global unit

  // --- B-fragments: tile0 = {i,f} x 8 units, tile1 = {g,o} x 8 units ---
  // col n<8 -> gate lowrow + unit ub+n ; n>=8 -> gate hi + unit ub+n-8
  unsigned long long bf0q[32], bf1q[32];   // [ks*2 + half]
  {
    int n  = lane & 15;
    int kb = (lane >> 4) * 8;
    long r0 = (n < 8) ? (long)(0 * 512 + ub + n) : (long)(1 * 512 + ub + n - 8);
    long r1 = (n < 8) ? (long)(2 * 512 + ub + n) : (long)(3 * 512 + ub + n - 8);
    const unsigned long long* w0 = (const unsigned long long*)(WhhB + r0 * 512);
    const unsigned long long* w1 = (const unsigned long long*)(WhhB + r1 * 512);
    #pragma unroll
    for (int ks = 0; ks < 16; ++ks) {
      int e = (ks * 32 + kb) >> 2;
      bf0q[ks * 2]     = w0[e];
      bf0q[ks * 2 + 1] = w0[e + 1];
      bf1q[ks * 2]     = w1[e];
      bf1q[ks * 2 + 1] = w1[e + 1];
    }
    // pin in VGPRs: value no longer provably equal to memory -> no remat
    #pragma unroll
    for (int i = 0; i < 32; ++i) {
      asm volatile("" : "+v"(bf0q[i]));
      asm volatile("" : "+v"(bf1q[i]));
    }
  }

  // elementwise cell assignment: lane c = lane&15, hi = c>=8, unit = ub + (c&7)
  const int c8  = lane & 15;
  const bool hi = (c8 >= 8);
  const int u_g = ub + (c8 & 7);
  const int b0  = q * 16 + (lane >> 4) * 4 + (hi ? 2 : 0);
  const int b1  = b0 + 1;

  const int arow = q * 16 + (lane & 15);   // A batch row (global)
  const int akk  = (lane >> 4) * 8;        // A k sub-offset

  float cst0 = 0.f, cst1 = 0.f;

  #pragma unroll 1
  for (int t = 0; t < S_LEN; ++t) {
    // x-gate prefetch: one 8B load per cell (i,f,g,o contiguous)
    const unsigned short* pt = pre + (long)t * (512 * 64 * 4);
    ushort4 pv0 = *(const ushort4*)(pt + ((long)u_g * 64 + b0) * 4);
    ushort4 pv1 = *(const ushort4*)(pt + ((long)u_g * 64 + b1) * 4);

    f32x4 p0a = (f32x4){0.f,0.f,0.f,0.f}, p0b = (f32x4){0.f,0.f,0.f,0.f};
    f32x4 p1a = (f32x4){0.f,0.f,0.f,0.f}, p1b = (f32x4){0.f,0.f,0.f,0.f};

    if (t > 0) {
      // poll own group's 64 per-wave flags: one dword per lane, coalesced
      while (true) {
        int v = __hip_atomic_load(&flags[q * 64 + lane], __ATOMIC_RELAXED,
                                  __HIP_MEMORY_SCOPE_AGENT);
        if (__all(v >= t)) break;
      }
      asm volatile("" ::: "memory");

      const unsigned long long* hb =
          (const unsigned long long*)(hbuf + (t & 1) * (BATCH * HID));
      // two halves of 8 k-steps: cap live A regs at 32 VGPRs
      #pragma unroll
      for (int half = 0; half < 2; ++half) {
        unsigned long long av[16];
        #pragma unroll
        for (int ks = 0; ks < 8; ++ks) {
          long e = ((long)arow * 512 + (half * 8 + ks) * 32 + akk) >> 2;
          av[ks * 2]     = __hip_atomic_load(hb + e,     __ATOMIC_RELAXED,
                                             __HIP_MEMORY_SCOPE_AGENT);
          av[ks * 2 + 1] = __hip_atomic_load(hb + e + 1, __ATOMIC_RELAXED,
                                             __HIP_MEMORY_SCOPE_AGENT);
        }
        #pragma unroll
        for (int ks = 0; ks < 8; ++ks) {
          int kk = half * 8 + ks;
          union { unsigned long long qq[2]; short8v v; } ua, ub0, ub1;
          ua.qq[0] = av[ks * 2]; ua.qq[1] = av[ks * 2 + 1];
          ub0.qq[0] = bf0q[kk * 2]; ub0.qq[1] = bf0q[kk * 2 + 1];
          ub1.qq[0] = bf1q[kk * 2]; ub1.qq[1] = bf1q[kk * 2 + 1];
          if (kk & 1) {
            p0b = __builtin_amdgcn_mfma_f32_16x16x32_bf16(ua.v, ub0.v, p0b, 0, 0, 0);
            p1b = __builtin_amdgcn_mfma_f32_16x16x32_bf16(ua.v, ub1.v, p1b, 0, 0, 0);
          } else {
            p0a = __builtin_amdgcn_mfma_f32_16x16x32_bf16(ua.v, ub0.v, p0a, 0, 0, 0);
            p1a = __builtin_amdgcn_mfma_f32_16x16x32_bf16(ua.v, ub1.v, p1a, 0, 0, 0);
          }
        }
      }
    }
    f32x4 A0 = p0a + p0b;   // tile0: cols {i x 8u | f x 8u}
    f32x4 A1 = p1a + p1b;   // tile1: cols {g x 8u | o x 8u}

    // in-wave gate exchange with lane^8 (each side sends what partner needs)
    float s0 = __shfl_xor(hi ? A0[0] : A0[2], 8);
    float s1 = __shfl_xor(hi ? A0[1] : A0[3], 8);
    float s2 = __shfl_xor(hi ? A1[0] : A1[2], 8);
    float s3 = __shfl_xor(hi ? A1[1] : A1[3], 8);

    float zi0 = (hi ? s0 : A0[0]) + bf2f(pv0.x);
    float zf0 = (hi ? A0[2] : s0) + bf2f(pv0.y);
    float zg0 = (hi ? s2 : A1[0]) + bf2f(pv0.z);
    float zo0 = (hi ? A1[2] : s2) + bf2f(pv0.w);
    float zi1 = (hi ? s1 : A0[1]) + bf2f(pv1.x);
    float zf1 = (hi ? A0[3] : s1) + bf2f(pv1.y);
    float zg1 = (hi ? s3 : A1[1]) + bf2f(pv1.z);
    float zo1 = (hi ? A1[3] : s3) + bf2f(pv1.w);

    float hv0, hv1, cv0, cv1;
    {
      float ii = 1.f / (1.f + __expf(-zi0));
      float ff = 1.f / (1.f + __expf(-zf0));
      float e1 = __expf(2.f * fminf(zg0, 15.f));
      float gg = (e1 - 1.f) / (e1 + 1.f);
      float oo = 1.f / (1.f + __expf(-zo0));
      float cn = ff * cst0 + ii * gg;
      float e2 = __expf(2.f * fminf(cn, 15.f));
      float tc = (e2 - 1.f) / (e2 + 1.f);
      cst0 = cn; cv0 = cn; hv0 = oo * tc;
    }
    {
      float ii = 1.f / (1.f + __expf(-zi1));
      float ff = 1.f / (1.f + __expf(-zf1));
      float e1 = __expf(2.f * fminf(zg1, 15.f));
      float gg = (e1 - 1.f) / (e1 + 1.f);
      float oo = 1.f / (1.f + __expf(-zo1));
      float cn = ff * cst1 + ii * gg;
      float e2 = __expf(2.f * fminf(cn, 15.f));
      float tc = (e2 - 1.f) / (e2 + 1.f);
      cst1 = cn; cv1 = cn; hv1 = oo * tc;
    }

    // pack unit pairs (even lane holds u, partner lane^1 holds u+1)
    unsigned short hb0 = f2bf(hv0), hb1 = f2bf(hv1);
    int o0 = __shfl_xor((int)hb0, 1);
    int o1 = __shfl_xor((int)hb1, 1);
    if (!(lane & 1)) {
      unsigned w0 = (unsigned)hb0 | ((unsigned)o0 << 16);
      unsigned w1 = (unsigned)hb1 | ((unsigned)o1 << 16);
      unsigned* hw = (unsigned*)(hbuf + ((t + 1) & 1) * (BATCH * HID));
      __hip_atomic_store(hw + ((b0 * HID + u_g) >> 1), w0, __ATOMIC_RELAXED,
                         __HIP_MEMORY_SCOPE_AGENT);
      __hip_atomic_store(hw + ((b1 * HID + u_g) >> 1), w1, __ATOMIC_RELAXED,
                         __HIP_MEMORY_SCOPE_AGENT);
    }
    // release: wave-local drain (only the 2 h words pending), then publish
    asm volatile("s_waitcnt vmcnt(0)" ::: "memory");
    if (lane == 0) {
      __hip_atomic_store(&flags[q * 64 + uo], t + 1, __ATOMIC_RELAXED,
                         __HIP_MEMORY_SCOPE_AGENT);
    }

    // out stores AFTER flag publish: off the critical path
    long ob = (long)t * (BATCH * HID);
    out[ob + (long)b0 * HID + u_g] = hv0;
    out[ob + (long)b1 * HID + u_g] = hv1;
    if (t == S_LEN - 1) {
      long fb = (long)S_LEN * (BATCH * HID);
      out[fb + (long)b0 * HID + u_g] = hv0;
      out[fb + (long)b1 * HID + u_g] = hv1;
      out[fb + BATCH * HID + (long)b0 * HID + u_g] = cv0;
      out[fb + BATCH * HID + (long)b1 * HID + u_g] = cv1;
    }
  }
}

extern "C" void kernel_launch(void* const* d_in, const int* in_sizes, int n_in,
                              void* d_out, int out_size, void* d_ws, size_t ws_size,
                              hipStream_t stream) {
  const float* x   = (const float*)d_in[0];
  const float* Wih = (const float*)d_in[1];
  const float* Whh = (const float*)d_in[2];
  const float* bih = (const float*)d_in[3];
  const float* bhh = (const float*)d_in[4];
  float* out = (float*)d_out;

  char* ws = (char*)d_ws;
  size_t off = 0;
  auto alloc = [&](size_t bytes) -> char* {
    char* p = ws + off;
    off += (bytes + 255) & ~(size_t)255;
    return p;
  };
  unsigned short* xhi  = (unsigned short*)alloc((size_t)S_LEN * BATCH * DIN * 2);
  unsigned short* xlo  = (unsigned short*)alloc((size_t)S_LEN * BATCH * DIN * 2);
  unsigned short* preb = (unsigned short*)alloc((size_t)S_LEN * GATES * BATCH * 2);
  unsigned short* WihB = (unsigned short*)alloc((size_t)GATES * DIN * 2);
  unsigned short* WhhB = (unsigned short*)alloc((size_t)GATES * DIN * 2);
  float*          bias = (float*)alloc((size_t)GATES * 4);
  unsigned short* hbuf = (unsigned short*)alloc((size_t)2 * BATCH * HID * 2);
  int*            flg  = (int*)alloc(4 * 64 * sizeof(int));

  hipMemsetAsync(flg, 0, 4 * 64 * sizeof(int), stream);  // replay-safe
  k_split_x<<<8192, 256, 0, stream>>>(x, xhi, xlo);
  k_prep_w<<<4096, 256, 0, stream>>>(Wih, Whh, bih, bhh, WihB, WhhB, bias);
  k_gemm_pre<<<16384, 256, 0, stream>>>(WihB, xhi, xlo, bias, preb);
  k_lstm<<<NBLK, 512, 0, stream>>>(preb, WhhB, hbuf, flg, out);
}

// Round 4
// 13083.389 us; speedup vs baseline: 1.9245x; 1.9245x over previous
//
#include <hip/hip_runtime.h>
#include <hip/hip_bf16.h>

#define S_LEN 2048
#define BATCH 64
#define HID   512
#define GATES 2048   // 4*HID
#define DIN   512

typedef __attribute__((ext_vector_type(8))) short short8v;
typedef __attribute__((ext_vector_type(4))) float f32x4;

__device__ inline unsigned short f2bf(float f) {
  union { float f; unsigned u; } a; a.f = f;
  unsigned r = a.u + 0x7fffu + ((a.u >> 16) & 1u);
  return (unsigned short)(r >> 16);
}
__device__ inline float bf2f(unsigned short h) {
  union { unsigned u; float f; } a; a.u = ((unsigned)h) << 16; return a.f;
}

// ---------- kernel 1: split x (fp32) -> bf16 hi + lo ----------
__global__ __launch_bounds__(256) void k_split_x(const float* __restrict__ x,
                                                 unsigned short* __restrict__ xhi,
                                                 unsigned short* __restrict__ xlo) {
  const long total = (long)S_LEN * BATCH * DIN / 4;
  long i = (long)blockIdx.x * blockDim.x + threadIdx.x;
  const long stride = (long)gridDim.x * blockDim.x;
  for (; i < total; i += stride) {
    float4 v = ((const float4*)x)[i];
    ushort4 hv, lv;
    hv.x = f2bf(v.x); lv.x = f2bf(v.x - bf2f(hv.x));
    hv.y = f2bf(v.y); lv.y = f2bf(v.y - bf2f(hv.y));
    hv.z = f2bf(v.z); lv.z = f2bf(v.z - bf2f(hv.z));
    hv.w = f2bf(v.w); lv.w = f2bf(v.w - bf2f(hv.w));
    ((ushort4*)xhi)[i] = hv;
    ((ushort4*)xlo)[i] = lv;
  }
}

// ---------- kernel 2: weights -> bf16, bias sum ----------
__global__ __launch_bounds__(256) void k_prep_w(const float* __restrict__ Wih,
                                                const float* __restrict__ Whh,
                                                const float* __restrict__ bih,
                                                const float* __restrict__ bhh,
                                                unsigned short* __restrict__ WihB,
                                                unsigned short* __restrict__ WhhB,
                                                float* __restrict__ bias) {
  int i = blockIdx.x * 256 + threadIdx.x;
  if (i < GATES * DIN) {
    WihB[i] = f2bf(Wih[i]);
    WhhB[i] = f2bf(Whh[i]);
  }
  if (i < GATES) bias[i] = bih[i] + bhh[i];
}

// ---------- kernel 3: pre[t][u][b][gate] = x[t,b,:]·Wih[gate*512+u,:] + biases ----------
#define BM 128
#define BN 128
#define BK 32
#define LDSROW 40

__global__ __launch_bounds__(256) void k_gemm_pre(
    const unsigned short* __restrict__ A,   // WihB [2048][512]
    const unsigned short* __restrict__ Bh,  // xhi  [131072][512]
    const unsigned short* __restrict__ Bl,  // xlo
    const float* __restrict__ bias,
    unsigned short* __restrict__ pre)       // [S][512 u][64 b][4 gate] bf16
{
  __shared__ unsigned short As [BM * LDSROW];
  __shared__ unsigned short Bhs[BM * LDSROW];
  __shared__ unsigned short Bls[BM * LDSROW];

  const int tid  = threadIdx.x;
  const int lane = tid & 63;
  const int wave = tid >> 6;
  const int bm = blockIdx.x & 15;
  const int bn = blockIdx.x >> 4;
  const int wr = wave >> 1, wc = wave & 1;

  f32x4 acc[4][4];
  #pragma unroll
  for (int i = 0; i < 4; ++i)
    #pragma unroll
    for (int j = 0; j < 4; ++j) acc[i][j] = (f32x4){0.f, 0.f, 0.f, 0.f};

  const long arow0 = (long)bm * BM;
  const long brow0 = (long)bn * BN;

  for (int kt = 0; kt < DIN / BK; ++kt) {
    #pragma unroll
    for (int it = 0; it < 2; ++it) {
      int c = tid + it * 256;
      int row = c >> 2, kc = c & 3;
      int lbyte = row * (LDSROW * 2) + kc * 16;
      long ga = (arow0 + row) * 512 + kt * BK + kc * 8;
      long gb = (brow0 + row) * 512 + kt * BK + kc * 8;
      *(short8v*)((char*)As  + lbyte) = *(const short8v*)(A  + ga);
      *(short8v*)((char*)Bhs + lbyte) = *(const short8v*)(Bh + gb);
      *(short8v*)((char*)Bls + lbyte) = *(const short8v*)(Bl + gb);
    }
    __syncthreads();

    short8v a[4], bh[4], bl[4];
    #pragma unroll
    for (int mt = 0; mt < 4; ++mt) {
      int r = wr * 64 + mt * 16 + (lane & 15);
      a[mt] = *(const short8v*)((const char*)As + r * (LDSROW * 2) + (lane >> 4) * 16);
    }
    #pragma unroll
    for (int nt = 0; nt < 4; ++nt) {
      int r = wc * 64 + nt * 16 + (lane & 15);
      bh[nt] = *(const short8v*)((const char*)Bhs + r * (LDSROW * 2) + (lane >> 4) * 16);
      bl[nt] = *(const short8v*)((const char*)Bls + r * (LDSROW * 2) + (lane >> 4) * 16);
    }
    #pragma unroll
    for (int mt = 0; mt < 4; ++mt)
      #pragma unroll
      for (int nt = 0; nt < 4; ++nt) {
        acc[mt][nt] = __builtin_amdgcn_mfma_f32_16x16x32_bf16(a[mt], bh[nt], acc[mt][nt], 0, 0, 0);
        acc[mt][nt] = __builtin_amdgcn_mfma_f32_16x16x32_bf16(a[mt], bl[nt], acc[mt][nt], 0, 0, 0);
      }
    __syncthreads();
  }

  #pragma unroll
  for (int mt = 0; mt < 4; ++mt) {
    #pragma unroll
    for (int j = 0; j < 4; ++j) {
      int m = bm * BM + wr * 64 + mt * 16 + (lane >> 4) * 4 + j;  // gate-row 0..2047
      int gate = m >> 9;
      int u    = m & 511;
      float bv = bias[m];
      #pragma unroll
      for (int nt = 0; nt < 4; ++nt) {
        int n = bn * BN + wc * 64 + nt * 16 + (lane & 15);
        int t = n >> 6, b = n & 63;
        pre[(((long)t * 512 + u) * 64 + b) * 4 + gate] = f2bf(acc[mt][nt][j] + bv);
      }
    }
  }
}

// ---------- kernel 4: persistent recurrence ----------
// 128 blocks x 256 threads = 512 waves on 128 CUs. Quad q = blockIdx>>5 owns
// batches [q*16, q*16+16); block ublk = blockIdx&31 owns units [ublk*16,+16);
// wave w owns units [ublk*16 + w*4, +4) with ALL 4 gates (gate-complete tile:
// 16 batches x 16 cols where col n = gate(n>>2), unit du(n&3)).
// Per-wave state: B-frags 64 VGPR + av 64 VGPR -> fits under (256,1) cap, no
// spill. Cell update needs only an in-wave LDS 4x4 gate transpose. Sync:
// per-block flags (32 per quad), sc1 MALL atomics, one __syncthreads per step
// (doubles as the vmcnt drain before flag publish).
__global__ __launch_bounds__(256, 1) void k_lstm(
    const unsigned short* __restrict__ pre,   // [S][512][64][4] bf16
    const unsigned short* __restrict__ WhhB,  // [2048][512] bf16
    unsigned short* __restrict__ hbuf,        // [2][64 b][512 u] bf16
    int* __restrict__ flags,                  // [4][32]
    float* __restrict__ out)                  // [S*B*H | h_f | c_f]
{
  __shared__ float ex[4][256];   // per-wave 1KB gate-transpose scratch

  const int tid  = threadIdx.x;
  const int lane = tid & 63;
  const int wave = tid >> 6;          // 0..3
  const int q    = blockIdx.x >> 5;   // batch quad 0..3
  const int ublk = blockIdx.x & 31;   // unit block 0..31
  const int ub   = ublk * 16 + wave * 4;  // first unit of this wave

  // --- B-fragments (one 16x16 tile, 64 VGPRs, held across all steps) ---
  unsigned long long bq[32];
  {
    int n  = lane & 15;
    int kb = (lane >> 4) * 8;
    long r = (long)((n >> 2) * 512 + ub + (n & 3)) * 512;
    const unsigned long long* w = (const unsigned long long*)(WhhB + r);
    #pragma unroll
    for (int ks = 0; ks < 16; ++ks) {
      int e = (ks * 32 + kb) >> 2;
      bq[ks * 2]     = w[e];
      bq[ks * 2 + 1] = w[e + 1];
    }
    #pragma unroll
    for (int i = 0; i < 32; ++i) asm volatile("" : "+v"(bq[i]));
  }

  // cell assignment: one cell per lane
  const int du = lane & 3;            // unit offset
  const int G  = (lane >> 2) & 3;     // row-within-rowgroup (also my gate col)
  const int rg = lane >> 4;           // row group
  const int b_g = q * 16 + rg * 4 + G;  // my batch
  const int u_g = ub + du;              // my unit

  // A-fragment addressing
  const int arow = q * 16 + (lane & 15);
  const int akk  = (lane >> 4) * 8;

  float cst = 0.f;

  #pragma unroll 1
  for (int t = 0; t < S_LEN; ++t) {
    // x-gates prefetch (8B, i/f/g/o contiguous) — issued before the poll
    ushort4 pv = *(const ushort4*)(pre + (((long)t * 512 + u_g) * 64 + b_g) * 4);

    f32x4 aa = (f32x4){0.f, 0.f, 0.f, 0.f};
    f32x4 ab = (f32x4){0.f, 0.f, 0.f, 0.f};

    if (t > 0) {
      // poll quad's 32 block-flags (one coalesced line); skip own block
      const int fi = lane & 31;
      while (true) {
        int v = (fi == ublk) ? 0x7fffffff
                             : __hip_atomic_load(&flags[q * 32 + fi],
                                                 __ATOMIC_RELAXED,
                                                 __HIP_MEMORY_SCOPE_AGENT);
        if (__all(v >= t)) break;
      }
      asm volatile("" ::: "memory");

      // A-fragments straight from MALL into VGPRs
      const unsigned long long* hb =
          (const unsigned long long*)(hbuf + (t & 1) * (BATCH * HID));
      unsigned long long av[32];
      #pragma unroll
      for (int ks = 0; ks < 16; ++ks) {
        long e = ((long)arow * 512 + ks * 32 + akk) >> 2;
        av[ks * 2]     = __hip_atomic_load(hb + e,     __ATOMIC_RELAXED,
                                           __HIP_MEMORY_SCOPE_AGENT);
        av[ks * 2 + 1] = __hip_atomic_load(hb + e + 1, __ATOMIC_RELAXED,
                                           __HIP_MEMORY_SCOPE_AGENT);
      }
      #pragma unroll
      for (int ks = 0; ks < 16; ++ks) {
        union { unsigned long long qq[2]; short8v v; } ua, ubf;
        ua.qq[0]  = av[ks * 2];     ua.qq[1]  = av[ks * 2 + 1];
        ubf.qq[0] = bq[ks * 2];     ubf.qq[1] = bq[ks * 2 + 1];
        if (ks & 1) ab = __builtin_amdgcn_mfma_f32_16x16x32_bf16(ua.v, ubf.v, ab, 0, 0, 0);
        else        aa = __builtin_amdgcn_mfma_f32_16x16x32_bf16(ua.v, ubf.v, aa, 0, 0, 0);
      }
    }
    f32x4 sum = aa + ab;   // acc[j]: batch row rg*4+j, col = 4*G_gate + du... (col=lane&15)

    // in-wave 4x4 gate transpose via LDS: write my col's 4 rows, read my row's 4 gates
    {
      *(f32x4*)&ex[wave][rg * 64 + du * 16 + G * 4] = sum;
      asm volatile("s_waitcnt lgkmcnt(0)" ::: "memory");
    }
    float zA0 = ex[wave][rg * 64 + du * 16 + 0 * 4 + G];
    float zA1 = ex[wave][rg * 64 + du * 16 + 1 * 4 + G];
    float zA2 = ex[wave][rg * 64 + du * 16 + 2 * 4 + G];
    float zA3 = ex[wave][rg * 64 + du * 16 + 3 * 4 + G];

    // cell update (1 cell per lane)
    float zi = zA0 + bf2f(pv.x);
    float zf = zA1 + bf2f(pv.y);
    float zg = zA2 + bf2f(pv.z);
    float zo = zA3 + bf2f(pv.w);
    float ii = 1.f / (1.f + __expf(-zi));
    float ff = 1.f / (1.f + __expf(-zf));
    float e1 = __expf(2.f * fminf(zg, 15.f));
    float gg = (e1 - 1.f) / (e1 + 1.f);
    float oo = 1.f / (1.f + __expf(-zo));
    float cn = ff * cst + ii * gg;
    float e2 = __expf(2.f * fminf(cn, 15.f));
    float tc = (e2 - 1.f) / (e2 + 1.f);
    float hv = oo * tc;
    cst = cn;

    // pack 4 units (du lanes 0..3 of same cell-row) into one u64, store sc1
    {
      unsigned v32 = (unsigned)f2bf(hv);
      unsigned p1 = (unsigned)__shfl_xor((int)v32, 1);
      unsigned w0 = (du & 1) ? (p1 | (v32 << 16)) : (v32 | (p1 << 16));
      unsigned p2 = (unsigned)__shfl_xor((int)w0, 2);
      if ((lane & 3) == 0) {
        unsigned long long W = (unsigned long long)w0 | ((unsigned long long)p2 << 32);
        unsigned long long* hw = (unsigned long long*)
            (hbuf + ((t + 1) & 1) * (BATCH * HID) + b_g * HID + ub);
        __hip_atomic_store(hw, W, __ATOMIC_RELAXED, __HIP_MEMORY_SCOPE_AGENT);
      }
    }

    // drain (all waves' h stores at MALL) then publish block flag
    asm volatile("s_waitcnt vmcnt(0)" ::: "memory");
    __syncthreads();
    if (tid == 0) {
      __hip_atomic_store(&flags[q * 32 + ublk], t + 1, __ATOMIC_RELAXED,
                         __HIP_MEMORY_SCOPE_AGENT);
    }

    // out stores after flag: off the critical path
    out[(long)t * (BATCH * HID) + (long)b_g * HID + u_g] = hv;
    if (t == S_LEN - 1) {
      long fb = (long)S_LEN * (BATCH * HID);
      out[fb + (long)b_g * HID + u_g] = hv;
      out[fb + BATCH * HID + (long)b_g * HID + u_g] = cn;
    }
  }
}

extern "C" void kernel_launch(void* const* d_in, const int* in_sizes, int n_in,
                              void* d_out, int out_size, void* d_ws, size_t ws_size,
                              hipStream_t stream) {
  const float* x   = (const float*)d_in[0];
  const float* Wih = (const float*)d_in[1];
  const float* Whh = (const float*)d_in[2];
  const float* bih = (const float*)d_in[3];
  const float* bhh = (const float*)d_in[4];
  float* out = (float*)d_out;

  char* ws = (char*)d_ws;
  size_t off = 0;
  auto alloc = [&](size_t bytes) -> char* {
    char* p = ws + off;
    off += (bytes + 255) & ~(size_t)255;
    return p;
  };
  unsigned short* xhi  = (unsigned short*)alloc((size_t)S_LEN * BATCH * DIN * 2);
  unsigned short* xlo  = (unsigned short*)alloc((size_t)S_LEN * BATCH * DIN * 2);
  unsigned short* preb = (unsigned short*)alloc((size_t)S_LEN * GATES * BATCH * 2);
  unsigned short* WihB = (unsigned short*)alloc((size_t)GATES * DIN * 2);
  unsigned short* WhhB = (unsigned short*)alloc((size_t)GATES * DIN * 2);
  float*          bias = (float*)alloc((size_t)GATES * 4);
  unsigned short* hbuf = (unsigned short*)alloc((size_t)2 * BATCH * HID * 2);
  int*            flg  = (int*)alloc(4 * 32 * sizeof(int));

  hipMemsetAsync(flg, 0, 4 * 32 * sizeof(int), stream);  // replay-safe
  k_split_x<<<8192, 256, 0, stream>>>(x, xhi, xlo);
  k_prep_w<<<4096, 256, 0, stream>>>(Wih, Whh, bih, bhh, WihB, WhhB, bias);
  k_gemm_pre<<<16384, 256, 0, stream>>>(WihB, xhi, xlo, bias, preb);
  k_lstm<<<128, 256, 0, stream>>>(preb, WhhB, hbuf, flg, out);
}